// Round 3
// baseline (339.022 us; speedup 1.0000x reference)
//
#include <hip/hip_runtime.h>
#include <hip/hip_bf16.h>

// Edge link-predictor: score = sigmoid(relu([h[src]|h[dst]] @ W1 + b1) @ W2 + b2)
// H=128, K=256, E=600000. bf16 MFMA (32x32x16).
// R3: no LDS A-tile. Each wave gathers its 32 edges' A-fragments directly
// global->VGPR (fragment layout == contiguous 16B slices of h rows).
// W1^T bf16 in LDS (64 KB, XOR-swizzled, conflict-free), staged once.
// 512-thread blocks, 8 independent waves, launch_bounds(512,4) -> 16 waves/CU.

#define HID   128
#define NEDGE 600000
#define TPB   512
#define WPB   8                    // waves per block
#define NBLK  512
#define NTIL  (NEDGE / 32)         // 18750 tiles of 32 edges, exact

typedef __attribute__((ext_vector_type(8)))  __bf16 bf16x8;
typedef __attribute__((ext_vector_type(16))) float  f32x16;

__global__ __launch_bounds__(TPB, 4) void edge_mlp_kernel(
    const float* __restrict__ h,  const float* __restrict__ W1,
    const float* __restrict__ b1, const float* __restrict__ W2,
    const float* __restrict__ b2, const int* __restrict__ src,
    const int* __restrict__ dst,  float* __restrict__ out)
{
    // W1^T bf16: row n (0..127), 256 k = 512 B/row. col-slot XOR-swizzle by
    // (n&31)<<4 -> 32 lanes of a b128 read hit 32 distinct 16B slots (0-conflict).
    __shared__ unsigned char smem[65536];

    const int t    = threadIdx.x;
    const int lane = t & 63;
    const int wv   = t >> 6;
    const int l31  = lane & 31;
    const int l5   = lane >> 5;

    // ---- detect index width (jnp.int64 vs int32 on device) ----
    bool idx64;
    {
        unsigned long long m =
            __ballot((src[2 * lane + 1] == 0) && (dst[2 * lane + 1] == 0));
        idx64 = (m == ~0ULL);
    }

    // ---- stage W1^T (f32 -> bf16, swizzled 16B writes), once ----
    for (int task = t; task < 4096; task += TPB) {
        int n    = task & 127;          // output col
        int slot = task >> 7;           // 16B slot = 8 consecutive k
        const float* wp = W1 + (slot * 8) * HID + n;
        bf16x8 v;
#pragma unroll
        for (int j = 0; j < 8; ++j) v[j] = (__bf16)wp[j * HID];
        *(bf16x8*)(smem + n * 512 + ((slot * 16) ^ ((n & 31) << 4))) = v;
    }

    // per-lane layer-2 constants: n = ct*32 + l31
    float b1v[4], w2v[4];
#pragma unroll
    for (int ct = 0; ct < 4; ++ct) {
        int n = ct * 32 + l31;
        b1v[ct] = b1[n];
        w2v[ct] = W2[n];
    }
    const float b2s = b2[0];
    __syncthreads();   // W1 staged; no further barriers

    const int swz = l31 << 4;   // B-read swizzle is per-lane constant

    const int gw = blockIdx.x * WPB + wv;
    for (int tile = gw; tile < NTIL; tile += NBLK * WPB) {
        const int e = tile * 32 + l31;
        const long long ns = idx64 ? (long long)src[2 * e] : (long long)src[e];
        const long long nd = idx64 ? (long long)dst[2 * e] : (long long)dst[e];
        const float* hs = h + ns * HID + l5 * 8;
        const float* hd = h + nd * HID + l5 * 8;

        f32x16 acc[4];
#pragma unroll
        for (int ct = 0; ct < 4; ++ct)
#pragma unroll
            for (int r = 0; r < 16; ++r) acc[ct][r] = 0.0f;

        // A-fragment for mfma_32x32x16: row = l31 (edge), k = ks*16 + l5*8 + j.
        // That is 32 contiguous bytes of h[node] at float offset ks*16 + l5*8.
#pragma unroll
        for (int ks = 0; ks < 16; ++ks) {
            const float* p = (ks < 8) ? (hs + ks * 16) : (hd + (ks - 8) * 16);
            float4 f0 = *(const float4*)p;
            float4 f1 = *(const float4*)(p + 4);
            bf16x8 af;
            af[0] = (__bf16)f0.x; af[1] = (__bf16)f0.y;
            af[2] = (__bf16)f0.z; af[3] = (__bf16)f0.w;
            af[4] = (__bf16)f1.x; af[5] = (__bf16)f1.y;
            af[6] = (__bf16)f1.z; af[7] = (__bf16)f1.w;
            const int coff = ks * 32 + l5 * 16;
#pragma unroll
            for (int ct = 0; ct < 4; ++ct) {
                const int n = ct * 32 + l31;
                bf16x8 bfg = *(const bf16x8*)(smem + n * 512 + (coff ^ swz));
                acc[ct] = __builtin_amdgcn_mfma_f32_32x32x16_bf16(af, bfg,
                                                                  acc[ct], 0, 0, 0);
            }
        }

        // ---- epilogue: bias+relu, dot W2, butterfly over 32 col-lanes ----
        float p[16];
#pragma unroll
        for (int r = 0; r < 16; ++r) p[r] = 0.0f;
#pragma unroll
        for (int ct = 0; ct < 4; ++ct) {
#pragma unroll
            for (int r = 0; r < 16; ++r) {
                float v = acc[ct][r] + b1v[ct];
                v = v > 0.0f ? v : 0.0f;
                p[r] += v * w2v[ct];
            }
        }
#pragma unroll
        for (int r = 0; r < 16; ++r) {
            p[r] += __shfl_xor(p[r], 1);
            p[r] += __shfl_xor(p[r], 2);
            p[r] += __shfl_xor(p[r], 4);
            p[r] += __shfl_xor(p[r], 8);
            p[r] += __shfl_xor(p[r], 16);
        }
        // C/D layout: row = (reg&3) + 8*(reg>>2) + 4*(lane>>5); col = lane&31.
        if (l31 == 0) {
#pragma unroll
            for (int g = 0; g < 4; ++g) {
                const int e0 = tile * 32 + g * 8 + l5 * 4;
                float4 o4;
                o4.x = 1.0f / (1.0f + __expf(-(p[4 * g + 0] + b2s)));
                o4.y = 1.0f / (1.0f + __expf(-(p[4 * g + 1] + b2s)));
                o4.z = 1.0f / (1.0f + __expf(-(p[4 * g + 2] + b2s)));
                o4.w = 1.0f / (1.0f + __expf(-(p[4 * g + 3] + b2s)));
                *(float4*)(out + e0) = o4;
            }
        }
    }
}

extern "C" void kernel_launch(void* const* d_in, const int* in_sizes, int n_in,
                              void* d_out, int out_size, void* d_ws, size_t ws_size,
                              hipStream_t stream) {
    const float* h  = (const float*)d_in[0];
    const float* W1 = (const float*)d_in[1];
    const float* b1 = (const float*)d_in[2];
    const float* W2 = (const float*)d_in[3];
    const float* b2 = (const float*)d_in[4];
    const int* src  = (const int*)d_in[5];
    const int* dst  = (const int*)d_in[6];
    (void)in_sizes; (void)n_in; (void)out_size; (void)d_ws; (void)ws_size;
    edge_mlp_kernel<<<NBLK, TPB, 0, stream>>>(h, W1, b1, W2, b2, src, dst,
                                              (float*)d_out);
}

// Round 4
// 198.261 us; speedup vs baseline: 1.7100x; 1.7100x over previous
//
#include <hip/hip_runtime.h>
#include <hip/hip_bf16.h>

// Edge link-predictor: score = sigmoid(relu([h[src]|h[dst]] @ W1 + b1) @ W2 + b2)
// H=128, K=256, E=600000. bf16 MFMA (32x32x16).
// R4: direct global->VGPR A-gather (no A LDS), W1^T bf16 in LDS (64 KB,
// swizzled, staged once). M=64 edges per wave (2 row-groups) so each W1
// fragment read from LDS feeds 2 MFMAs. acc = 128 f32/lane, statically
// indexed. launch_bounds(256,2): 2 blocks/CU (min-blocks semantics observed
// in R3!), VGPR cap 256, LDS 2x64KB=128<=160, 8 waves/CU.

#define HID   128
#define NEDGE 600000
#define TPB   256
#define NBLK  512
#define NTIL  (NEDGE / 64)         // 9375 tiles of 64 edges, exact

typedef __attribute__((ext_vector_type(8)))  __bf16 bf16x8;
typedef __attribute__((ext_vector_type(16))) float  f32x16;

__global__ __launch_bounds__(TPB, 2) void edge_mlp_kernel(
    const float* __restrict__ h,  const float* __restrict__ W1,
    const float* __restrict__ b1, const float* __restrict__ W2,
    const float* __restrict__ b2, const int* __restrict__ src,
    const int* __restrict__ dst,  float* __restrict__ out)
{
    // W1^T bf16: row n (0..127), 256 k = 512 B/row; 16B-slot XOR swizzle by
    // (n&31)<<4 -> a wave's 32-row b128 read hits all 32 banks evenly.
    __shared__ unsigned char smem[65536];

    const int t    = threadIdx.x;
    const int lane = t & 63;
    const int wv   = t >> 6;
    const int l31  = lane & 31;
    const int l5   = lane >> 5;

    // ---- detect index width (jnp.int64 vs int32 on device) ----
    bool idx64;
    {
        unsigned long long m =
            __ballot((src[2 * lane + 1] == 0) && (dst[2 * lane + 1] == 0));
        idx64 = (m == ~0ULL);
    }

    // ---- stage W1^T (f32 -> bf16 via v_cvt_pk, swizzled), once ----
    for (int task = t; task < 4096; task += TPB) {
        int n    = task & 127;          // output col (consecutive lanes -> coalesced)
        int slot = task >> 7;           // 16B slot = 8 consecutive k
        const float* wp = W1 + (slot * 8) * HID + n;
        bf16x8 v;
#pragma unroll
        for (int j = 0; j < 8; ++j) v[j] = (__bf16)wp[j * HID];
        *(bf16x8*)(smem + n * 512 + ((slot * 16) ^ ((n & 31) << 4))) = v;
    }

    // per-lane layer-2 constants: n = ct*32 + l31
    float b1v[4], w2v[4];
#pragma unroll
    for (int ct = 0; ct < 4; ++ct) {
        int n = ct * 32 + l31;
        b1v[ct] = b1[n];
        w2v[ct] = W2[n];
    }
    const float b2s = b2[0];
    __syncthreads();   // W1 staged; no further barriers

    const int swz = l31 << 4;   // B-read swizzle is a per-lane constant

    const int gw = blockIdx.x * 4 + wv;
    for (int tile = gw; tile < NTIL; tile += NBLK * 4) {
        // two row-groups: edges e0 (rows 0-31) and e1 (rows 32-63)
        const int e0 = tile * 64 + l31;
        const int e1 = e0 + 32;
        const long long ns0 = idx64 ? (long long)src[2 * e0] : (long long)src[e0];
        const long long nd0 = idx64 ? (long long)dst[2 * e0] : (long long)dst[e0];
        const long long ns1 = idx64 ? (long long)src[2 * e1] : (long long)src[e1];
        const long long nd1 = idx64 ? (long long)dst[2 * e1] : (long long)dst[e1];
        const float* hs0 = h + ns0 * HID + l5 * 8;
        const float* hd0 = h + nd0 * HID + l5 * 8;
        const float* hs1 = h + ns1 * HID + l5 * 8;
        const float* hd1 = h + nd1 * HID + l5 * 8;

        f32x16 acc0[4], acc1[4];
#pragma unroll
        for (int ct = 0; ct < 4; ++ct)
#pragma unroll
            for (int r = 0; r < 16; ++r) { acc0[ct][r] = 0.0f; acc1[ct][r] = 0.0f; }

        // A-frag (32x32x16): row = l31, k = ks*16 + l5*8 + j  ->  32 contiguous
        // bytes of h[node] at float offset ks*16 (+ l5*8 folded into base ptr).
#pragma unroll
        for (int ks = 0; ks < 16; ++ks) {
            const float* p0 = (ks < 8) ? (hs0 + ks * 16) : (hd0 + (ks - 8) * 16);
            const float* p1 = (ks < 8) ? (hs1 + ks * 16) : (hd1 + (ks - 8) * 16);
            float4 a0 = *(const float4*)p0;
            float4 a1 = *(const float4*)(p0 + 4);
            float4 c0 = *(const float4*)p1;
            float4 c1 = *(const float4*)(p1 + 4);
            bf16x8 af0, af1;
            af0[0] = (__bf16)a0.x; af0[1] = (__bf16)a0.y;
            af0[2] = (__bf16)a0.z; af0[3] = (__bf16)a0.w;
            af0[4] = (__bf16)a1.x; af0[5] = (__bf16)a1.y;
            af0[6] = (__bf16)a1.z; af0[7] = (__bf16)a1.w;
            af1[0] = (__bf16)c0.x; af1[1] = (__bf16)c0.y;
            af1[2] = (__bf16)c0.z; af1[3] = (__bf16)c0.w;
            af1[4] = (__bf16)c1.x; af1[5] = (__bf16)c1.y;
            af1[6] = (__bf16)c1.z; af1[7] = (__bf16)c1.w;
            const int coff = ks * 32 + l5 * 16;
#pragma unroll
            for (int ct = 0; ct < 4; ++ct) {
                const int n = ct * 32 + l31;
                bf16x8 bfg = *(const bf16x8*)(smem + n * 512 + (coff ^ swz));
                acc0[ct] = __builtin_amdgcn_mfma_f32_32x32x16_bf16(af0, bfg,
                                                                   acc0[ct], 0, 0, 0);
                acc1[ct] = __builtin_amdgcn_mfma_f32_32x32x16_bf16(af1, bfg,
                                                                   acc1[ct], 0, 0, 0);
            }
        }

        // ---- epilogue per row-group: bias+relu, dot W2, butterfly, store ----
#pragma unroll
        for (int rg = 0; rg < 2; ++rg) {
            float p[16];
#pragma unroll
            for (int r = 0; r < 16; ++r) p[r] = 0.0f;
#pragma unroll
            for (int ct = 0; ct < 4; ++ct) {
#pragma unroll
                for (int r = 0; r < 16; ++r) {
                    float v = (rg ? acc1[ct][r] : acc0[ct][r]) + b1v[ct];
                    v = v > 0.0f ? v : 0.0f;
                    p[r] += v * w2v[ct];
                }
            }
#pragma unroll
            for (int r = 0; r < 16; ++r) {
                p[r] += __shfl_xor(p[r], 1);
                p[r] += __shfl_xor(p[r], 2);
                p[r] += __shfl_xor(p[r], 4);
                p[r] += __shfl_xor(p[r], 8);
                p[r] += __shfl_xor(p[r], 16);
            }
            // C/D layout: row = (r&3) + 8*(r>>2) + 4*l5; col = l31.
            if (l31 == 0) {
#pragma unroll
                for (int g = 0; g < 4; ++g) {
                    const int eo = tile * 64 + rg * 32 + g * 8 + l5 * 4;
                    float4 o4;
                    o4.x = 1.0f / (1.0f + __expf(-(p[4 * g + 0] + b2s)));
                    o4.y = 1.0f / (1.0f + __expf(-(p[4 * g + 1] + b2s)));
                    o4.z = 1.0f / (1.0f + __expf(-(p[4 * g + 2] + b2s)));
                    o4.w = 1.0f / (1.0f + __expf(-(p[4 * g + 3] + b2s)));
                    *(float4*)(out + eo) = o4;
                }
            }
        }
    }
}

extern "C" void kernel_launch(void* const* d_in, const int* in_sizes, int n_in,
                              void* d_out, int out_size, void* d_ws, size_t ws_size,
                              hipStream_t stream) {
    const float* h  = (const float*)d_in[0];
    const float* W1 = (const float*)d_in[1];
    const float* b1 = (const float*)d_in[2];
    const float* W2 = (const float*)d_in[3];
    const float* b2 = (const float*)d_in[4];
    const int* src  = (const int*)d_in[5];
    const int* dst  = (const int*)d_in[6];
    (void)in_sizes; (void)n_in; (void)out_size; (void)d_ws; (void)ws_size;
    edge_mlp_kernel<<<NBLK, TPB, 0, stream>>>(h, W1, b1, W2, b2, src, dst,
                                              (float*)d_out);
}

// Round 5
// 181.369 us; speedup vs baseline: 1.8692x; 1.0931x over previous
//
#include <hip/hip_runtime.h>
#include <hip/hip_bf16.h>

// Edge link-predictor: score = sigmoid(relu([h[src]|h[dst]] @ W1 + b1) @ W2 + b2)
// H=128, K=256, E=600000. bf16 MFMA (32x32x16).
// R5: R4 structure with controlled register pressure.
//  - direct global->VGPR A-gather (no A LDS, no per-tile barriers)
//  - W1^T bf16 in LDS (64 KB, XOR-swizzled -> 0 bank conflicts, staged once)
//  - M=32 edges/wave (acc = 64 f32/lane, statically indexed)
//  - __launch_bounds__(256,1): the only config measured spill-free (R2: 232
//    VGPR, WRITE=2.4MB). R3's (512,4) -> 64 VGPR cap -> 232MB scratch;
//    R4's (256,2) -> 128 cap -> 95MB scratch. Spill is the #1 failure mode.

#define HID   128
#define NEDGE 600000
#define TPB   256
#define NBLK  512
#define NTIL  (NEDGE / 32)         // 18750 tiles of 32 edges, exact

typedef __attribute__((ext_vector_type(8)))  __bf16 bf16x8;
typedef __attribute__((ext_vector_type(16))) float  f32x16;

__global__ __launch_bounds__(TPB, 1) void edge_mlp_kernel(
    const float* __restrict__ h,  const float* __restrict__ W1,
    const float* __restrict__ b1, const float* __restrict__ W2,
    const float* __restrict__ b2, const int* __restrict__ src,
    const int* __restrict__ dst,  float* __restrict__ out)
{
    // W1^T bf16: row n (0..127), 256 k = 512 B/row; 16B-slot XOR swizzle by
    // (n&31)<<4 -> a wave's b128 B-read achieves the 8-cycle bank floor
    // (verified: SQ_LDS_BANK_CONFLICT = 0 in R4).
    __shared__ unsigned char smem[65536];

    const int t    = threadIdx.x;
    const int lane = t & 63;
    const int wv   = t >> 6;
    const int l31  = lane & 31;
    const int l5   = lane >> 5;

    // ---- detect index width (jnp.int64 vs int32 on device) ----
    bool idx64;
    {
        unsigned long long m =
            __ballot((src[2 * lane + 1] == 0) && (dst[2 * lane + 1] == 0));
        idx64 = (m == ~0ULL);
    }

    // ---- stage W1^T (f32 -> bf16 via v_cvt_pk, swizzled), once per block ----
    for (int task = t; task < 4096; task += TPB) {
        int n    = task & 127;          // output col
        int slot = task >> 7;           // 16B slot = 8 consecutive k
        const float* wp = W1 + (slot * 8) * HID + n;
        bf16x8 v;
#pragma unroll
        for (int j = 0; j < 8; ++j) v[j] = (__bf16)wp[j * HID];
        *(bf16x8*)(smem + n * 512 + ((slot * 16) ^ ((n & 31) << 4))) = v;
    }

    // per-lane layer-2 constants: n = ct*32 + l31
    float b1v[4], w2v[4];
#pragma unroll
    for (int ct = 0; ct < 4; ++ct) {
        int n = ct * 32 + l31;
        b1v[ct] = b1[n];
        w2v[ct] = W2[n];
    }
    const float b2s = b2[0];
    __syncthreads();   // W1 staged; no further barriers

    const int swz = l31 << 4;   // B-read swizzle is a per-lane constant

    const int gw = blockIdx.x * 4 + wv;
    for (int tile = gw; tile < NTIL; tile += NBLK * 4) {
        const int e = tile * 32 + l31;
        const long long ns = idx64 ? (long long)src[2 * e] : (long long)src[e];
        const long long nd = idx64 ? (long long)dst[2 * e] : (long long)dst[e];
        const float* hs = h + ns * HID + l5 * 8;
        const float* hd = h + nd * HID + l5 * 8;

        f32x16 acc[4];
#pragma unroll
        for (int ct = 0; ct < 4; ++ct)
#pragma unroll
            for (int r = 0; r < 16; ++r) acc[ct][r] = 0.0f;

        // A-frag (32x32x16): row = l31 (edge), k = ks*16 + l5*8 + j ->
        // 32 contiguous bytes of h[node] at float offset ks*16 (l5*8 in base).
#pragma unroll
        for (int ks = 0; ks < 16; ++ks) {
            const float* p = (ks < 8) ? (hs + ks * 16) : (hd + (ks - 8) * 16);
            float4 f0 = *(const float4*)p;
            float4 f1 = *(const float4*)(p + 4);
            bf16x8 af;
            af[0] = (__bf16)f0.x; af[1] = (__bf16)f0.y;
            af[2] = (__bf16)f0.z; af[3] = (__bf16)f0.w;
            af[4] = (__bf16)f1.x; af[5] = (__bf16)f1.y;
            af[6] = (__bf16)f1.z; af[7] = (__bf16)f1.w;
            const int coff = ks * 32 + l5 * 16;
#pragma unroll
            for (int ct = 0; ct < 4; ++ct) {
                const int n = ct * 32 + l31;
                bf16x8 bfg = *(const bf16x8*)(smem + n * 512 + (coff ^ swz));
                acc[ct] = __builtin_amdgcn_mfma_f32_32x32x16_bf16(af, bfg,
                                                                  acc[ct], 0, 0, 0);
            }
        }

        // ---- epilogue: bias+relu, dot W2, butterfly over 32 col-lanes ----
        float p[16];
#pragma unroll
        for (int r = 0; r < 16; ++r) p[r] = 0.0f;
#pragma unroll
        for (int ct = 0; ct < 4; ++ct) {
#pragma unroll
            for (int r = 0; r < 16; ++r) {
                float v = acc[ct][r] + b1v[ct];
                v = v > 0.0f ? v : 0.0f;
                p[r] += v * w2v[ct];
            }
        }
#pragma unroll
        for (int r = 0; r < 16; ++r) {
            p[r] += __shfl_xor(p[r], 1);
            p[r] += __shfl_xor(p[r], 2);
            p[r] += __shfl_xor(p[r], 4);
            p[r] += __shfl_xor(p[r], 8);
            p[r] += __shfl_xor(p[r], 16);
        }
        // C/D layout: row = (r&3) + 8*(r>>2) + 4*l5; col = l31.
        if (l31 == 0) {
#pragma unroll
            for (int g = 0; g < 4; ++g) {
                const int e0 = tile * 32 + g * 8 + l5 * 4;
                float4 o4;
                o4.x = 1.0f / (1.0f + __expf(-(p[4 * g + 0] + b2s)));
                o4.y = 1.0f / (1.0f + __expf(-(p[4 * g + 1] + b2s)));
                o4.z = 1.0f / (1.0f + __expf(-(p[4 * g + 2] + b2s)));
                o4.w = 1.0f / (1.0f + __expf(-(p[4 * g + 3] + b2s)));
                *(float4*)(out + e0) = o4;
            }
        }
    }
}

extern "C" void kernel_launch(void* const* d_in, const int* in_sizes, int n_in,
                              void* d_out, int out_size, void* d_ws, size_t ws_size,
                              hipStream_t stream) {
    const float* h  = (const float*)d_in[0];
    const float* W1 = (const float*)d_in[1];
    const float* b1 = (const float*)d_in[2];
    const float* W2 = (const float*)d_in[3];
    const float* b2 = (const float*)d_in[4];
    const int* src  = (const int*)d_in[5];
    const int* dst  = (const int*)d_in[6];
    (void)in_sizes; (void)n_in; (void)out_size; (void)d_ws; (void)ws_size;
    edge_mlp_kernel<<<NBLK, TPB, 0, stream>>>(h, W1, b1, W2, b2, src, dst,
                                              (float*)d_out);
}

// Round 6
// 110.677 us; speedup vs baseline: 3.0632x; 1.6387x over previous
//
#include <hip/hip_runtime.h>
#include <hip/hip_bf16.h>

// score = sigmoid(relu([h[src]|h[dst]]@W1 + b1) @ W2 + b2)
// R6 restructuring: concat-Linear == h[src]@W1a + h[dst]@W1b.
//   K1: per-NODE uv[n] = [h@W1a | h@W1b] bf16 into d_ws  (3.3 GFLOP MFMA)
//   K2: per-edge  sigmoid(relu(u[src]+v[dst]+b1)·W2 + b2) (memory-bound)
// 12x less matrix work than the per-edge GEMM formulation.

#define HID    128
#define NNODE  50000
#define NEDGE  600000
#define NGRP   ((NNODE + 31) / 32)       // 1563 node groups of 32
#define K1BLK  ((NGRP + 1) / 2)          // 782 blocks, 2 groups each
#define K2BLK  1024

typedef __attribute__((ext_vector_type(8)))  __bf16 bf16x8;
typedef __attribute__((ext_vector_type(16))) float  f32x16;

static __device__ __forceinline__ unsigned int pack2bf(float a, float b) {
    unsigned int ua = __float_as_uint(a);
    unsigned int ub = __float_as_uint(b);
    ua = (ua + 0x7FFFu + ((ua >> 16) & 1u)) >> 16;
    ub = (ub + 0x7FFFu + ((ub >> 16) & 1u)) >> 16;
    return (ub << 16) | (ua & 0xFFFFu);
}

// ---------------- K1: node GEMM  uv[50000][256] bf16 ----------------
// uv[i][j<128] = (h[i]@W1a)[j],  uv[i][128+j] = (h[i]@W1b)[j]
__global__ __launch_bounds__(256, 2) void node_gemm_kernel(
    const float* __restrict__ h, const float* __restrict__ W1,
    unsigned short* __restrict__ uvs)
{
    // W1cat^T bf16: row n' (0..255), 128 k = 256 B/row, slot swizzle (n&15)<<4.
    __shared__ unsigned char smem[65536];
    const int t = threadIdx.x, lane = t & 63, wv = t >> 6;
    const int l31 = lane & 31, l5 = lane >> 5;

    // stage W1cat^T: n'<128 -> W1[k][n'], n'>=128 -> W1[128+k][n'-128]
    for (int task = t; task < 4096; task += 256) {
        int n = task & 255, slot = task >> 8;       // slot = 8 consecutive k
        const float* wp = (n < 128) ? (W1 + (slot * 8) * HID + n)
                                    : (W1 + (128 + slot * 8) * HID + (n - 128));
        bf16x8 v;
#pragma unroll
        for (int j = 0; j < 8; ++j) v[j] = (__bf16)wp[j * HID];
        *(bf16x8*)(smem + n * 256 + ((slot * 16) ^ ((n & 15) << 4))) = v;
    }
    __syncthreads();

    const int group = blockIdx.x * 2 + (wv >> 1);   // wave-pair per group
    if (group >= NGRP) return;
    const int nof0 = (wv & 1) * 128;                // this wave's 128 cols

    const int node  = group * 32 + l31;
    const int nodec = node < NNODE ? node : NNODE - 1;
    const float* hp = h + (size_t)nodec * HID + l5 * 8;

    f32x16 acc[4];
#pragma unroll
    for (int ct = 0; ct < 4; ++ct)
#pragma unroll
        for (int r = 0; r < 16; ++r) acc[ct][r] = 0.0f;

    // A-frag: row=l31(node), k = ks*16 + l5*8 + j  (K=128 -> ks 0..7)
#pragma unroll
    for (int ks = 0; ks < 8; ++ks) {
        float4 f0 = *(const float4*)(hp + ks * 16);
        float4 f1 = *(const float4*)(hp + ks * 16 + 4);
        bf16x8 af;
        af[0] = (__bf16)f0.x; af[1] = (__bf16)f0.y;
        af[2] = (__bf16)f0.z; af[3] = (__bf16)f0.w;
        af[4] = (__bf16)f1.x; af[5] = (__bf16)f1.y;
        af[6] = (__bf16)f1.z; af[7] = (__bf16)f1.w;
        const int koff = ks * 32 + l5 * 16;
#pragma unroll
        for (int ct = 0; ct < 4; ++ct) {
            const int n = nof0 + ct * 32 + l31;
            bf16x8 bfg = *(const bf16x8*)(smem + n * 256 +
                                          (koff ^ ((n & 15) << 4)));
            acc[ct] = __builtin_amdgcn_mfma_f32_32x32x16_bf16(af, bfg,
                                                              acc[ct], 0, 0, 0);
        }
    }

    // store: C row=(r&3)+8*(r>>2)+4*l5 (node), col=nof0+ct*32+l31.
    // pack col pairs across lane l31^1 -> 4-B bf16x2 stores.
#pragma unroll
    for (int ct = 0; ct < 4; ++ct) {
#pragma unroll
        for (int r = 0; r < 16; ++r) {
            float mine = acc[ct][r];
            float partner = __shfl_xor(mine, 1);
            if (!(l31 & 1)) {
                const int rr = (r & 3) + 8 * (r >> 2) + 4 * l5;
                const int nd = group * 32 + rr;
                if (nd < NNODE) {
                    const int n = nof0 + ct * 32 + l31;
                    *(unsigned int*)(uvs + (size_t)nd * 256 + n) =
                        pack2bf(mine, partner);
                }
            }
        }
    }
}

// ---------------- K2: edge gather + tiny MLP tail ----------------
__global__ __launch_bounds__(256, 4) void edge_score_kernel(
    const unsigned short* __restrict__ uvs, const float* __restrict__ b1,
    const float* __restrict__ W2, const float* __restrict__ b2,
    const int* __restrict__ src, const int* __restrict__ dst,
    float* __restrict__ out)
{
    const int t = threadIdx.x, lane = t & 63, wv = t >> 6;
    const int chunk = lane & 15;        // 16-B chunk within half-row
    const int role  = (lane >> 4) & 1;  // 0 = u(src), 1 = v(dst)
    const int esel  = lane >> 5;        // which edge of this pass

    bool idx64;
    {
        unsigned long long m =
            __ballot((src[2 * lane + 1] == 0) && (dst[2 * lane + 1] == 0));
        idx64 = (m == ~0ULL);
    }

    float b1f[8], w2f[8];
#pragma unroll
    for (int j = 0; j < 8; ++j) {
        b1f[j] = b1[chunk * 8 + j];
        w2f[j] = W2[chunk * 8 + j];
    }
    const float b2s = b2[0];

    const int gw = blockIdx.x * 4 + wv;
    const int NW = K2BLK * 4;
    for (int pass = gw; pass < NEDGE / 2; pass += NW) {
        const int e = pass * 2 + esel;
        const int node = role ? (idx64 ? dst[2 * e] : dst[e])
                              : (idx64 ? src[2 * e] : src[e]);
        const uint4 q = *(const uint4*)(uvs + (size_t)node * 256 +
                                        role * 128 + chunk * 8);
        float f[8];
        f[0] = __uint_as_float(q.x << 16);
        f[1] = __uint_as_float(q.x & 0xFFFF0000u);
        f[2] = __uint_as_float(q.y << 16);
        f[3] = __uint_as_float(q.y & 0xFFFF0000u);
        f[4] = __uint_as_float(q.z << 16);
        f[5] = __uint_as_float(q.z & 0xFFFF0000u);
        f[6] = __uint_as_float(q.w << 16);
        f[7] = __uint_as_float(q.w & 0xFFFF0000u);

        float p = 0.0f;
#pragma unroll
        for (int j = 0; j < 8; ++j) {
            float s = f[j] + __shfl_xor(f[j], 16) + b1f[j];  // u + v + b1
            s = s > 0.0f ? s : 0.0f;
            p = fmaf(s, w2f[j], p);
        }
        p += __shfl_xor(p, 1);
        p += __shfl_xor(p, 2);
        p += __shfl_xor(p, 4);
        p += __shfl_xor(p, 8);

        if ((lane & 31) == 0)
            out[e] = 1.0f / (1.0f + __expf(-(p + b2s)));
    }
}

// ---------------- fallback (R5, proven): used only if ws too small ----------
__global__ __launch_bounds__(256, 1) void edge_mlp_fallback(
    const float* __restrict__ h,  const float* __restrict__ W1,
    const float* __restrict__ b1, const float* __restrict__ W2,
    const float* __restrict__ b2, const int* __restrict__ src,
    const int* __restrict__ dst,  float* __restrict__ out)
{
    __shared__ unsigned char smem[65536];
    const int t = threadIdx.x, lane = t & 63, wv = t >> 6;
    const int l31 = lane & 31, l5 = lane >> 5;
    bool idx64;
    {
        unsigned long long m =
            __ballot((src[2 * lane + 1] == 0) && (dst[2 * lane + 1] == 0));
        idx64 = (m == ~0ULL);
    }
    for (int task = t; task < 4096; task += 256) {
        int n = task & 127, slot = task >> 7;
        const float* wp = W1 + (slot * 8) * HID + n;
        bf16x8 v;
#pragma unroll
        for (int j = 0; j < 8; ++j) v[j] = (__bf16)wp[j * HID];
        *(bf16x8*)(smem + n * 512 + ((slot * 16) ^ ((n & 31) << 4))) = v;
    }
    float b1v[4], w2v[4];
#pragma unroll
    for (int ct = 0; ct < 4; ++ct) {
        int n = ct * 32 + l31;
        b1v[ct] = b1[n]; w2v[ct] = W2[n];
    }
    const float b2s = b2[0];
    __syncthreads();
    const int swz = l31 << 4;
    const int gw = blockIdx.x * 4 + wv;
    for (int tile = gw; tile < NEDGE / 32; tile += 512 * 4) {
        const int e = tile * 32 + l31;
        const long long ns = idx64 ? (long long)src[2 * e] : (long long)src[e];
        const long long nd = idx64 ? (long long)dst[2 * e] : (long long)dst[e];
        const float* hs = h + ns * HID + l5 * 8;
        const float* hd = h + nd * HID + l5 * 8;
        f32x16 acc[4];
#pragma unroll
        for (int ct = 0; ct < 4; ++ct)
#pragma unroll
            for (int r = 0; r < 16; ++r) acc[ct][r] = 0.0f;
#pragma unroll
        for (int ks = 0; ks < 16; ++ks) {
            const float* p = (ks < 8) ? (hs + ks * 16) : (hd + (ks - 8) * 16);
            float4 f0 = *(const float4*)p;
            float4 f1 = *(const float4*)(p + 4);
            bf16x8 af;
            af[0] = (__bf16)f0.x; af[1] = (__bf16)f0.y;
            af[2] = (__bf16)f0.z; af[3] = (__bf16)f0.w;
            af[4] = (__bf16)f1.x; af[5] = (__bf16)f1.y;
            af[6] = (__bf16)f1.z; af[7] = (__bf16)f1.w;
            const int coff = ks * 32 + l5 * 16;
#pragma unroll
            for (int ct = 0; ct < 4; ++ct) {
                const int n = ct * 32 + l31;
                bf16x8 bfg = *(const bf16x8*)(smem + n * 512 + (coff ^ swz));
                acc[ct] = __builtin_amdgcn_mfma_f32_32x32x16_bf16(af, bfg,
                                                                  acc[ct], 0, 0, 0);
            }
        }
        float p[16];
#pragma unroll
        for (int r = 0; r < 16; ++r) p[r] = 0.0f;
#pragma unroll
        for (int ct = 0; ct < 4; ++ct)
#pragma unroll
            for (int r = 0; r < 16; ++r) {
                float v = acc[ct][r] + b1v[ct];
                v = v > 0.0f ? v : 0.0f;
                p[r] += v * w2v[ct];
            }
#pragma unroll
        for (int r = 0; r < 16; ++r) {
            p[r] += __shfl_xor(p[r], 1);  p[r] += __shfl_xor(p[r], 2);
            p[r] += __shfl_xor(p[r], 4);  p[r] += __shfl_xor(p[r], 8);
            p[r] += __shfl_xor(p[r], 16);
        }
        if (l31 == 0) {
#pragma unroll
            for (int g = 0; g < 4; ++g) {
                const int e0 = tile * 32 + g * 8 + l5 * 4;
                float4 o4;
                o4.x = 1.0f / (1.0f + __expf(-(p[4 * g + 0] + b2s)));
                o4.y = 1.0f / (1.0f + __expf(-(p[4 * g + 1] + b2s)));
                o4.z = 1.0f / (1.0f + __expf(-(p[4 * g + 2] + b2s)));
                o4.w = 1.0f / (1.0f + __expf(-(p[4 * g + 3] + b2s)));
                *(float4*)(out + e0) = o4;
            }
        }
    }
}

extern "C" void kernel_launch(void* const* d_in, const int* in_sizes, int n_in,
                              void* d_out, int out_size, void* d_ws, size_t ws_size,
                              hipStream_t stream) {
    const float* h  = (const float*)d_in[0];
    const float* W1 = (const float*)d_in[1];
    const float* b1 = (const float*)d_in[2];
    const float* W2 = (const float*)d_in[3];
    const float* b2 = (const float*)d_in[4];
    const int* src  = (const int*)d_in[5];
    const int* dst  = (const int*)d_in[6];
    (void)in_sizes; (void)n_in; (void)out_size;

    const size_t need = (size_t)NNODE * 256 * 2;   // uv bf16 = 25.6 MB
    if (ws_size >= need) {
        node_gemm_kernel<<<K1BLK, 256, 0, stream>>>(h, W1,
                                                    (unsigned short*)d_ws);
        edge_score_kernel<<<K2BLK, 256, 0, stream>>>(
            (const unsigned short*)d_ws, b1, W2, b2, src, dst, (float*)d_out);
    } else {
        edge_mlp_fallback<<<512, 256, 0, stream>>>(h, W1, b1, W2, b2, src, dst,
                                                   (float*)d_out);
    }
}

// Round 7
// 76.168 us; speedup vs baseline: 4.4510x; 1.4531x over previous
//
#include <hip/hip_runtime.h>
#include <hip/hip_bf16.h>

// score = sigmoid(relu([h[src]|h[dst]]@W1 + b1) @ W2 + b2)
// R7: two-phase (R6) with latency-oriented fixes.
//   K1: per-NODE uv[n] = [h@W1a | h@W1b] bf16 -> d_ws. Persistent 320 blocks
//       (grid-stride) so W1 is staged 320x not 782x.
//   K2: per-edge tail. NEW layout: 16 lanes per edge, each lane loads BOTH
//       u-chunk (src) and v-chunk (dst) -> u+v merge is a local add; only
//       4 reduce shuffles per 4 edges (was 24). Grid 1536 @ (256,6):
//       24 waves/CU ceiling, VGPR cap 85 (spill-safe, kernel needs ~40).

#define HID    128
#define NNODE  50000
#define NEDGE  600000
#define NGRP   ((NNODE + 31) / 32)       // 1563 node groups of 32
#define NUNIT  ((NGRP + 1) / 2)          // 782 group-pairs
#define K1BLK  320
#define K2BLK  1536

typedef __attribute__((ext_vector_type(8)))  __bf16 bf16x8;
typedef __attribute__((ext_vector_type(16))) float  f32x16;

static __device__ __forceinline__ unsigned int pack2bf(float a, float b) {
    unsigned int ua = __float_as_uint(a);
    unsigned int ub = __float_as_uint(b);
    ua = (ua + 0x7FFFu + ((ua >> 16) & 1u)) >> 16;
    ub = (ub + 0x7FFFu + ((ub >> 16) & 1u)) >> 16;
    return (ub << 16) | (ua & 0xFFFFu);
}

// ---------------- K1: node GEMM  uv[50000][256] bf16 ----------------
// uv[i][j<128] = (h[i]@W1a)[j],  uv[i][128+j] = (h[i]@W1b)[j]
__global__ __launch_bounds__(256, 2) void node_gemm_kernel(
    const float* __restrict__ h, const float* __restrict__ W1,
    unsigned short* __restrict__ uvs)
{
    // W1cat^T bf16: row n' (0..255), 128 k = 256 B/row, slot swizzle (n&15)<<4.
    __shared__ unsigned char smem[65536];
    const int t = threadIdx.x, lane = t & 63, wv = t >> 6;
    const int l31 = lane & 31, l5 = lane >> 5;

    // stage W1cat^T once per block (reads are coalesced across threads per j)
    for (int task = t; task < 4096; task += 256) {
        int n = task & 255, slot = task >> 8;       // slot = 8 consecutive k
        const float* wp = (n < 128) ? (W1 + (slot * 8) * HID + n)
                                    : (W1 + (128 + slot * 8) * HID + (n - 128));
        bf16x8 v;
#pragma unroll
        for (int j = 0; j < 8; ++j) v[j] = (__bf16)wp[j * HID];
        *(bf16x8*)(smem + n * 256 + ((slot * 16) ^ ((n & 15) << 4))) = v;
    }
    __syncthreads();

    const int nof0 = (wv & 1) * 128;                // this wave's 128 cols

    for (int unit = blockIdx.x; unit < NUNIT; unit += K1BLK) {
        const int group = unit * 2 + (wv >> 1);
        if (group >= NGRP) continue;

        const int node  = group * 32 + l31;
        const int nodec = node < NNODE ? node : NNODE - 1;
        const float* hp = h + (size_t)nodec * HID + l5 * 8;

        f32x16 acc[4];
#pragma unroll
        for (int ct = 0; ct < 4; ++ct)
#pragma unroll
            for (int r = 0; r < 16; ++r) acc[ct][r] = 0.0f;

        // A-frag: row=l31(node), k = ks*16 + l5*8 + j  (K=128 -> ks 0..7)
#pragma unroll
        for (int ks = 0; ks < 8; ++ks) {
            float4 f0 = *(const float4*)(hp + ks * 16);
            float4 f1 = *(const float4*)(hp + ks * 16 + 4);
            bf16x8 af;
            af[0] = (__bf16)f0.x; af[1] = (__bf16)f0.y;
            af[2] = (__bf16)f0.z; af[3] = (__bf16)f0.w;
            af[4] = (__bf16)f1.x; af[5] = (__bf16)f1.y;
            af[6] = (__bf16)f1.z; af[7] = (__bf16)f1.w;
            const int koff = ks * 32 + l5 * 16;
#pragma unroll
            for (int ct = 0; ct < 4; ++ct) {
                const int n = nof0 + ct * 32 + l31;
                bf16x8 bfg = *(const bf16x8*)(smem + n * 256 +
                                              (koff ^ ((n & 15) << 4)));
                acc[ct] = __builtin_amdgcn_mfma_f32_32x32x16_bf16(af, bfg,
                                                                  acc[ct], 0, 0, 0);
            }
        }

        // store: C row=(r&3)+8*(r>>2)+4*l5 (node), col=nof0+ct*32+l31.
        // pack col pairs across lane l31^1 -> 4-B bf16x2 stores.
#pragma unroll
        for (int ct = 0; ct < 4; ++ct) {
#pragma unroll
            for (int r = 0; r < 16; ++r) {
                float mine = acc[ct][r];
                float partner = __shfl_xor(mine, 1);
                if (!(l31 & 1)) {
                    const int rr = (r & 3) + 8 * (r >> 2) + 4 * l5;
                    const int nd = group * 32 + rr;
                    if (nd < NNODE) {
                        const int n = nof0 + ct * 32 + l31;
                        *(unsigned int*)(uvs + (size_t)nd * 256 + n) =
                            pack2bf(mine, partner);
                    }
                }
            }
        }
    }
}

// ---------------- K2: edge gather + tiny MLP tail ----------------
// 16 lanes per edge (4 edges per wave). Lane (c = lane&15) loads u-chunk c of
// src and v-chunk c of dst; merge is local; 4-step butterfly over 16 lanes.
__global__ __launch_bounds__(256, 6) void edge_score_kernel(
    const unsigned short* __restrict__ uvs, const float* __restrict__ b1,
    const float* __restrict__ W2, const float* __restrict__ b2,
    const int* __restrict__ src, const int* __restrict__ dst,
    float* __restrict__ out)
{
    const int t = threadIdx.x, lane = t & 63, wv = t >> 6;
    const int c = lane & 15;        // 16-B chunk within 128-col half
    const int g = lane >> 4;        // edge-in-quad 0..3

    bool idx64;
    {
        unsigned long long m =
            __ballot((src[2 * lane + 1] == 0) && (dst[2 * lane + 1] == 0));
        idx64 = (m == ~0ULL);
    }

    float b1f[8], w2f[8];
#pragma unroll
    for (int j = 0; j < 8; ++j) {
        b1f[j] = b1[c * 8 + j];
        w2f[j] = W2[c * 8 + j];
    }
    const float b2s = b2[0];

    const int gw = blockIdx.x * 4 + wv;
    const int NQ = NEDGE / 4;                 // 150000 quads, exact
    for (int q = gw; q < NQ; q += K2BLK * 4) {
        const int e  = q * 4 + g;
        const int ns = idx64 ? src[2 * e] : src[e];
        const int nd = idx64 ? dst[2 * e] : dst[e];
        const uint4 qu = *(const uint4*)(uvs + (size_t)ns * 256 + c * 8);
        const uint4 qv = *(const uint4*)(uvs + (size_t)nd * 256 + 128 + c * 8);

        float p = 0.0f;
#pragma unroll
        for (int j = 0; j < 4; ++j) {
            const unsigned int uw = j == 0 ? qu.x : j == 1 ? qu.y : j == 2 ? qu.z : qu.w;
            const unsigned int vw = j == 0 ? qv.x : j == 1 ? qv.y : j == 2 ? qv.z : qv.w;
            float slo = __uint_as_float(uw << 16) + __uint_as_float(vw << 16)
                        + b1f[2 * j];
            float shi = __uint_as_float(uw & 0xFFFF0000u)
                        + __uint_as_float(vw & 0xFFFF0000u) + b1f[2 * j + 1];
            slo = slo > 0.0f ? slo : 0.0f;
            shi = shi > 0.0f ? shi : 0.0f;
            p = fmaf(slo, w2f[2 * j], p);
            p = fmaf(shi, w2f[2 * j + 1], p);
        }
        p += __shfl_xor(p, 1);
        p += __shfl_xor(p, 2);
        p += __shfl_xor(p, 4);
        p += __shfl_xor(p, 8);

        if (c == 0)                          // 4 lanes store 4 consecutive floats
            out[e] = 1.0f / (1.0f + __expf(-(p + b2s)));
    }
}

extern "C" void kernel_launch(void* const* d_in, const int* in_sizes, int n_in,
                              void* d_out, int out_size, void* d_ws, size_t ws_size,
                              hipStream_t stream) {
    const float* h  = (const float*)d_in[0];
    const float* W1 = (const float*)d_in[1];
    const float* b1 = (const float*)d_in[2];
    const float* W2 = (const float*)d_in[3];
    const float* b2 = (const float*)d_in[4];
    const int* src  = (const int*)d_in[5];
    const int* dst  = (const int*)d_in[6];
    (void)in_sizes; (void)n_in; (void)out_size; (void)ws_size;

    node_gemm_kernel<<<K1BLK, 256, 0, stream>>>(h, W1, (unsigned short*)d_ws);
    edge_score_kernel<<<K2BLK, 256, 0, stream>>>(
        (const unsigned short*)d_ws, b1, W2, b2, src, dst, (float*)d_out);
}

// Round 8
// 75.878 us; speedup vs baseline: 4.4680x; 1.0038x over previous
//
#include <hip/hip_runtime.h>
#include <hip/hip_bf16.h>

// score = sigmoid(relu([h[src]|h[dst]]@W1 + b1) @ W2 + b2)
// R8: two-phase.
//   K1 (782 blocks, one group-pair each): uv[n] = [h@W1a + b1 | h@W1b] bf16.
//      b1 folded into the u-half at store time (frees K2's inner loop).
//   K2 (2048 blocks @ (256,8) -> 8 blk/CU, 32 waves/CU): per-edge tail,
//      16 lanes/edge, unroll-2 software pipeline: idx loads for BOTH
//      sub-iters, then all 4 uv loads, then VALU -> 2x MLP per wave.

#define HID    128
#define NNODE  50000
#define NEDGE  600000
#define NGRP   ((NNODE + 31) / 32)       // 1563 node groups of 32
#define K1BLK  ((NGRP + 1) / 2)          // 782 blocks, 2 groups each
#define K2BLK  2048

typedef __attribute__((ext_vector_type(8)))  __bf16 bf16x8;
typedef __attribute__((ext_vector_type(16))) float  f32x16;

static __device__ __forceinline__ unsigned int pack2bf(float a, float b) {
    unsigned int ua = __float_as_uint(a);
    unsigned int ub = __float_as_uint(b);
    ua = (ua + 0x7FFFu + ((ua >> 16) & 1u)) >> 16;
    ub = (ub + 0x7FFFu + ((ub >> 16) & 1u)) >> 16;
    return (ub << 16) | (ua & 0xFFFFu);
}

// ---------------- K1: node GEMM  uv[50000][256] bf16 ----------------
// uv[i][j<128] = (h[i]@W1a)[j] + b1[j],  uv[i][128+j] = (h[i]@W1b)[j]
__global__ __launch_bounds__(256, 2) void node_gemm_kernel(
    const float* __restrict__ h, const float* __restrict__ W1,
    const float* __restrict__ b1, unsigned short* __restrict__ uvs)
{
    // W1cat^T bf16: row n' (0..255), 128 k = 256 B/row, slot swizzle (n&15)<<4.
    __shared__ unsigned char smem[65536];
    const int t = threadIdx.x, lane = t & 63, wv = t >> 6;
    const int l31 = lane & 31, l5 = lane >> 5;

    // stage W1cat^T (reads coalesced across lanes for each j)
    for (int task = t; task < 4096; task += 256) {
        int n = task & 255, slot = task >> 8;       // slot = 8 consecutive k
        const float* wp = (n < 128) ? (W1 + (slot * 8) * HID + n)
                                    : (W1 + (128 + slot * 8) * HID + (n - 128));
        bf16x8 v;
#pragma unroll
        for (int j = 0; j < 8; ++j) v[j] = (__bf16)wp[j * HID];
        *(bf16x8*)(smem + n * 256 + ((slot * 16) ^ ((n & 15) << 4))) = v;
    }
    __syncthreads();

    const int group = blockIdx.x * 2 + (wv >> 1);   // wave-pair per group
    if (group >= NGRP) return;
    const int nof0 = (wv & 1) * 128;                // this wave's 128 cols

    // b1 fold: only the u-half (nof0==0) waves add b1 to their columns.
    const float baddf = (nof0 == 0) ? 1.0f : 0.0f;
    float b1v[4];
#pragma unroll
    for (int ct = 0; ct < 4; ++ct) b1v[ct] = baddf * b1[ct * 32 + l31];

    const int node  = group * 32 + l31;
    const int nodec = node < NNODE ? node : NNODE - 1;
    const float* hp = h + (size_t)nodec * HID + l5 * 8;

    f32x16 acc[4];
#pragma unroll
    for (int ct = 0; ct < 4; ++ct)
#pragma unroll
        for (int r = 0; r < 16; ++r) acc[ct][r] = 0.0f;

    // A-frag: row=l31(node), k = ks*16 + l5*8 + j  (K=128 -> ks 0..7)
#pragma unroll
    for (int ks = 0; ks < 8; ++ks) {
        float4 f0 = *(const float4*)(hp + ks * 16);
        float4 f1 = *(const float4*)(hp + ks * 16 + 4);
        bf16x8 af;
        af[0] = (__bf16)f0.x; af[1] = (__bf16)f0.y;
        af[2] = (__bf16)f0.z; af[3] = (__bf16)f0.w;
        af[4] = (__bf16)f1.x; af[5] = (__bf16)f1.y;
        af[6] = (__bf16)f1.z; af[7] = (__bf16)f1.w;
        const int koff = ks * 32 + l5 * 16;
#pragma unroll
        for (int ct = 0; ct < 4; ++ct) {
            const int n = nof0 + ct * 32 + l31;
            bf16x8 bfg = *(const bf16x8*)(smem + n * 256 +
                                          (koff ^ ((n & 15) << 4)));
            acc[ct] = __builtin_amdgcn_mfma_f32_32x32x16_bf16(af, bfg,
                                                              acc[ct], 0, 0, 0);
        }
    }

    // store: C row=(r&3)+8*(r>>2)+4*l5 (node), col=nof0+ct*32+l31.
    // each lane adds ITS column's b1 (u-half) BEFORE the pair shuffle.
#pragma unroll
    for (int ct = 0; ct < 4; ++ct) {
#pragma unroll
        for (int r = 0; r < 16; ++r) {
            float mine = acc[ct][r] + b1v[ct];
            float partner = __shfl_xor(mine, 1);
            if (!(l31 & 1)) {
                const int rr = (r & 3) + 8 * (r >> 2) + 4 * l5;
                const int nd = group * 32 + rr;
                if (nd < NNODE) {
                    const int n = nof0 + ct * 32 + l31;
                    *(unsigned int*)(uvs + (size_t)nd * 256 + n) =
                        pack2bf(mine, partner);
                }
            }
        }
    }
}

// ---------------- K2: edge gather + tiny MLP tail ----------------
// 16 lanes per edge (4 edges/wave). Lane c loads u-chunk c of src and
// v-chunk c of dst. Unroll-2 pipeline: all idx loads, then all 4 table
// loads, then VALU. b1 already folded into u.
__global__ __launch_bounds__(256, 8) void edge_score_kernel(
    const unsigned short* __restrict__ uvs,
    const float* __restrict__ W2, const float* __restrict__ b2,
    const int* __restrict__ src, const int* __restrict__ dst,
    float* __restrict__ out)
{
    const int t = threadIdx.x, lane = t & 63, wv = t >> 6;
    const int c = lane & 15;        // 16-B chunk within 128-col half
    const int g = lane >> 4;        // edge-in-quad 0..3

    bool idx64;
    {
        unsigned long long m =
            __ballot((src[2 * lane + 1] == 0) && (dst[2 * lane + 1] == 0));
        idx64 = (m == ~0ULL);
    }

    float w2f[8];
#pragma unroll
    for (int j = 0; j < 8; ++j) w2f[j] = W2[c * 8 + j];
    const float b2s = b2[0];

    const int gw = blockIdx.x * 4 + wv;
    const int NW = K2BLK * 4;                 // 8192 waves
    const int NQ = NEDGE / 4;                 // 150000 quads

    for (int q0 = gw; q0 < NQ; q0 += 2 * NW) {
        const int q1  = q0 + NW;
        const int q1c = q1 < NQ ? q1 : NQ - 1;      // clamp loads, guard store
        const int e0  = q0 * 4 + g;
        const int e1  = q1c * 4 + g;

        // ---- phase 1: all index loads ----
        const int ns0 = idx64 ? src[2 * e0] : src[e0];
        const int nd0 = idx64 ? dst[2 * e0] : dst[e0];
        const int ns1 = idx64 ? src[2 * e1] : src[e1];
        const int nd1 = idx64 ? dst[2 * e1] : dst[e1];

        // ---- phase 2: all table loads (4 in flight) ----
        const uint4 qu0 = *(const uint4*)(uvs + (size_t)ns0 * 256 + c * 8);
        const uint4 qv0 = *(const uint4*)(uvs + (size_t)nd0 * 256 + 128 + c * 8);
        const uint4 qu1 = *(const uint4*)(uvs + (size_t)ns1 * 256 + c * 8);
        const uint4 qv1 = *(const uint4*)(uvs + (size_t)nd1 * 256 + 128 + c * 8);

        // ---- phase 3: VALU ----
#pragma unroll
        for (int half = 0; half < 2; ++half) {
            const uint4 qu = half ? qu1 : qu0;
            const uint4 qv = half ? qv1 : qv0;
            float p = 0.0f;
#pragma unroll
            for (int j = 0; j < 4; ++j) {
                const unsigned int uw = j == 0 ? qu.x : j == 1 ? qu.y
                                      : j == 2 ? qu.z : qu.w;
                const unsigned int vw = j == 0 ? qv.x : j == 1 ? qv.y
                                      : j == 2 ? qv.z : qv.w;
                float slo = __uint_as_float(uw << 16)
                          + __uint_as_float(vw << 16);
                float shi = __uint_as_float(uw & 0xFFFF0000u)
                          + __uint_as_float(vw & 0xFFFF0000u);
                slo = slo > 0.0f ? slo : 0.0f;
                shi = shi > 0.0f ? shi : 0.0f;
                p = fmaf(slo, w2f[2 * j], p);
                p = fmaf(shi, w2f[2 * j + 1], p);
            }
            p += __shfl_xor(p, 1);
            p += __shfl_xor(p, 2);
            p += __shfl_xor(p, 4);
            p += __shfl_xor(p, 8);

            if (c == 0 && (half == 0 || q1 < NQ)) {
                const int e = half ? e1 : e0;   // 4 lanes -> 4 consecutive floats
                out[e] = 1.0f / (1.0f + __expf(-(p + b2s)));
            }
        }
    }
}

extern "C" void kernel_launch(void* const* d_in, const int* in_sizes, int n_in,
                              void* d_out, int out_size, void* d_ws, size_t ws_size,
                              hipStream_t stream) {
    const float* h  = (const float*)d_in[0];
    const float* W1 = (const float*)d_in[1];
    const float* b1 = (const float*)d_in[2];
    const float* W2 = (const float*)d_in[3];
    const float* b2 = (const float*)d_in[4];
    const int* src  = (const int*)d_in[5];
    const int* dst  = (const int*)d_in[6];
    (void)in_sizes; (void)n_in; (void)out_size; (void)ws_size;

    node_gemm_kernel<<<K1BLK, 256, 0, stream>>>(h, W1, b1,
                                                (unsigned short*)d_ws);
    edge_score_kernel<<<K2BLK, 256, 0, stream>>>(
        (const unsigned short*)d_ws, W2, b2, src, dst, (float*)d_out);
}

// Round 9
// 71.276 us; speedup vs baseline: 4.7565x; 1.0646x over previous
//
#include <hip/hip_runtime.h>
#include <hip/hip_bf16.h>

// score = sigmoid(relu([h[src]|h[dst]]@W1 + b1) @ W2 + b2)
// R9: three-kernel chain.
//   K0: W1 -> bf16 fragment-ordered table (64 KB) in d_ws (after uv). ~2 us.
//   K1: node GEMM, NO LDS/barriers. B-frags = coalesced 16B/lane reads of the
//       frag-ordered table (L2-hot); A-frags from h. 1 wave = 32 nodes x 128
//       cols. uv[n] = [h@W1a + b1 | h@W1b] bf16.
//   K2: per-edge tail (unchanged from R8: 42 us, occ 68%, VGPR 24).

#define HID    128
#define NNODE  50000
#define NEDGE  600000
#define NGRP   ((NNODE + 31) / 32)       // 1563 node groups of 32
#define K1BLK  ((NGRP + 1) / 2)          // 782 blocks, 2 groups (4 waves) each
#define K2BLK  2048
#define UVBYTES ((size_t)NNODE * 256 * 2)   // 25.6 MB
#define WTFRAG_OFF UVBYTES                  // frag-ordered W1T, 64 KB

typedef __attribute__((ext_vector_type(8)))  __bf16 bf16x8;
typedef __attribute__((ext_vector_type(16))) float  f32x16;

static __device__ __forceinline__ unsigned int pack2bf(float a, float b) {
    unsigned int ua = __float_as_uint(a);
    unsigned int ub = __float_as_uint(b);
    ua = (ua + 0x7FFFu + ((ua >> 16) & 1u)) >> 16;
    ub = (ub + 0x7FFFu + ((ub >> 16) & 1u)) >> 16;
    return (ub << 16) | (ua & 0xFFFFu);
}

// ---------------- K0: W1 -> bf16 fragment-ordered table ----------------
// Element (colhalf,ct,ks,l5,l31,j) at short-offset FIDX*256 + l31*8 + j,
// FIDX = ((colhalf*4+ct)*8+ks)*2+l5, value = W1[colhalf*128 + ks*16+l5*8+j][ct*32+l31].
// With T = FIDX*32+l31 the 16-B store lands at byte T*16 (fully coalesced).
__global__ __launch_bounds__(256, 1) void w1_frag_kernel(
    const float* __restrict__ W1, unsigned short* __restrict__ w1tf)
{
    const int T = blockIdx.x * 256 + threadIdx.x;   // 4096 threads
    const int l31  = T & 31;
    const int FIDX = T >> 5;
    const int l5 = FIDX & 1, ks = (FIDX >> 1) & 7;
    const int ct = (FIDX >> 4) & 3, colhalf = FIDX >> 6;
    const int kb = colhalf * 128 + ks * 16 + l5 * 8;
    const int n  = ct * 32 + l31;
    bf16x8 v;
#pragma unroll
    for (int j = 0; j < 8; ++j) v[j] = (__bf16)W1[(kb + j) * HID + n];
    *(bf16x8*)(w1tf + (size_t)T * 8) = v;
}

// ---------------- K1: node GEMM  uv[50000][256] bf16, no LDS ----------------
__global__ __launch_bounds__(256, 1) void node_gemm_kernel(
    const float* __restrict__ h, const unsigned short* __restrict__ w1tf,
    const float* __restrict__ b1, unsigned short* __restrict__ uvs)
{
    const int t = threadIdx.x, lane = t & 63, wv = t >> 6;
    const int l31 = lane & 31, l5 = lane >> 5;

    const int group = blockIdx.x * 2 + (wv >> 1);
    if (group >= NGRP) return;
    const int colhalf = wv & 1;                 // 0 -> u cols, 1 -> v cols

    // b1 fold: only the u-half adds b1 (per-column).
    float b1v[4];
#pragma unroll
    for (int ct = 0; ct < 4; ++ct)
        b1v[ct] = (colhalf == 0) ? b1[ct * 32 + l31] : 0.0f;

    const int node  = group * 32 + l31;
    const int nodec = node < NNODE ? node : NNODE - 1;
    const float* hp = h + (size_t)nodec * HID + l5 * 8;

    f32x16 acc[4];
#pragma unroll
    for (int ct = 0; ct < 4; ++ct)
#pragma unroll
        for (int r = 0; r < 16; ++r) acc[ct][r] = 0.0f;

    // per ks: 1 A-frag (h row slice) + 4 B-frags (coalesced 16B/lane) + 4 MFMA
#pragma unroll
    for (int ks = 0; ks < 8; ++ks) {
        float4 f0 = *(const float4*)(hp + ks * 16);
        float4 f1 = *(const float4*)(hp + ks * 16 + 4);
        bf16x8 af;
        af[0] = (__bf16)f0.x; af[1] = (__bf16)f0.y;
        af[2] = (__bf16)f0.z; af[3] = (__bf16)f0.w;
        af[4] = (__bf16)f1.x; af[5] = (__bf16)f1.y;
        af[6] = (__bf16)f1.z; af[7] = (__bf16)f1.w;
#pragma unroll
        for (int ct = 0; ct < 4; ++ct) {
            const int fidx = ((colhalf * 4 + ct) * 8 + ks) * 2 + l5;
            bf16x8 bfg = *(const bf16x8*)(w1tf + (size_t)fidx * 256 + l31 * 8);
            acc[ct] = __builtin_amdgcn_mfma_f32_32x32x16_bf16(af, bfg,
                                                              acc[ct], 0, 0, 0);
        }
    }

    // store: C row=(r&3)+8*(r>>2)+4*l5 (node), col = colhalf*128+ct*32+l31.
    // add b1 (u-half) before the pair shuffle; pack col pairs -> 4-B stores.
#pragma unroll
    for (int ct = 0; ct < 4; ++ct) {
#pragma unroll
        for (int r = 0; r < 16; ++r) {
            float mine = acc[ct][r] + b1v[ct];
            float partner = __shfl_xor(mine, 1);
            if (!(l31 & 1)) {
                const int rr = (r & 3) + 8 * (r >> 2) + 4 * l5;
                const int nd = group * 32 + rr;
                if (nd < NNODE) {
                    const int n = colhalf * 128 + ct * 32 + l31;
                    *(unsigned int*)(uvs + (size_t)nd * 256 + n) =
                        pack2bf(mine, partner);
                }
            }
        }
    }
}

// ---------------- K2: edge gather + tiny MLP tail (R8, proven) ----------------
__global__ __launch_bounds__(256, 8) void edge_score_kernel(
    const unsigned short* __restrict__ uvs,
    const float* __restrict__ W2, const float* __restrict__ b2,
    const int* __restrict__ src, const int* __restrict__ dst,
    float* __restrict__ out)
{
    const int t = threadIdx.x, lane = t & 63, wv = t >> 6;
    const int c = lane & 15;        // 16-B chunk within 128-col half
    const int g = lane >> 4;        // edge-in-quad 0..3

    bool idx64;
    {
        unsigned long long m =
            __ballot((src[2 * lane + 1] == 0) && (dst[2 * lane + 1] == 0));
        idx64 = (m == ~0ULL);
    }

    float w2f[8];
#pragma unroll
    for (int j = 0; j < 8; ++j) w2f[j] = W2[c * 8 + j];
    const float b2s = b2[0];

    const int gw = blockIdx.x * 4 + wv;
    const int NW = K2BLK * 4;
    const int NQ = NEDGE / 4;

    for (int q0 = gw; q0 < NQ; q0 += 2 * NW) {
        const int q1  = q0 + NW;
        const int q1c = q1 < NQ ? q1 : NQ - 1;
        const int e0  = q0 * 4 + g;
        const int e1  = q1c * 4 + g;

        const int ns0 = idx64 ? src[2 * e0] : src[e0];
        const int nd0 = idx64 ? dst[2 * e0] : dst[e0];
        const int ns1 = idx64 ? src[2 * e1] : src[e1];
        const int nd1 = idx64 ? dst[2 * e1] : dst[e1];

        const uint4 qu0 = *(const uint4*)(uvs + (size_t)ns0 * 256 + c * 8);
        const uint4 qv0 = *(const uint4*)(uvs + (size_t)nd0 * 256 + 128 + c * 8);
        const uint4 qu1 = *(const uint4*)(uvs + (size_t)ns1 * 256 + c * 8);
        const uint4 qv1 = *(const uint4*)(uvs + (size_t)nd1 * 256 + 128 + c * 8);

#pragma unroll
        for (int half = 0; half < 2; ++half) {
            const uint4 qu = half ? qu1 : qu0;
            const uint4 qv = half ? qv1 : qv0;
            float p = 0.0f;
#pragma unroll
            for (int j = 0; j < 4; ++j) {
                const unsigned int uw = j == 0 ? qu.x : j == 1 ? qu.y
                                      : j == 2 ? qu.z : qu.w;
                const unsigned int vw = j == 0 ? qv.x : j == 1 ? qv.y
                                      : j == 2 ? qv.z : qv.w;
                float slo = __uint_as_float(uw << 16)
                          + __uint_as_float(vw << 16);
                float shi = __uint_as_float(uw & 0xFFFF0000u)
                          + __uint_as_float(vw & 0xFFFF0000u);
                slo = slo > 0.0f ? slo : 0.0f;
                shi = shi > 0.0f ? shi : 0.0f;
                p = fmaf(slo, w2f[2 * j], p);
                p = fmaf(shi, w2f[2 * j + 1], p);
            }
            p += __shfl_xor(p, 1);
            p += __shfl_xor(p, 2);
            p += __shfl_xor(p, 4);
            p += __shfl_xor(p, 8);

            if (c == 0 && (half == 0 || q1 < NQ)) {
                const int e = half ? e1 : e0;
                out[e] = 1.0f / (1.0f + __expf(-(p + b2s)));
            }
        }
    }
}

// ---------------- fallback (proven single-kernel) ----------------
__global__ __launch_bounds__(256, 1) void edge_mlp_fallback(
    const float* __restrict__ h,  const float* __restrict__ W1,
    const float* __restrict__ b1, const float* __restrict__ W2,
    const float* __restrict__ b2, const int* __restrict__ src,
    const int* __restrict__ dst,  float* __restrict__ out)
{
    __shared__ unsigned char smem[65536];
    const int t = threadIdx.x, lane = t & 63, wv = t >> 6;
    const int l31 = lane & 31, l5 = lane >> 5;
    bool idx64;
    {
        unsigned long long m =
            __ballot((src[2 * lane + 1] == 0) && (dst[2 * lane + 1] == 0));
        idx64 = (m == ~0ULL);
    }
    for (int task = t; task < 4096; task += 256) {
        int n = task & 127, slot = task >> 7;
        const float* wp = W1 + (slot * 8) * HID + n;
        bf16x8 v;
#pragma unroll
        for (int j = 0; j < 8; ++j) v[j] = (__bf16)wp[j * HID];
        *(bf16x8*)(smem + n * 512 + ((slot * 16) ^ ((n & 31) << 4))) = v;
    }
    float b1v[4], w2v[4];
#pragma unroll
    for (int ct = 0; ct < 4; ++ct) {
        int n = ct * 32 + l31;
        b1v[ct] = b1[n]; w2v[ct] = W2[n];
    }
    const float b2s = b2[0];
    __syncthreads();
    const int swz = l31 << 4;
    const int gw = blockIdx.x * 4 + wv;
    for (int tile = gw; tile < NEDGE / 32; tile += 512 * 4) {
        const int e = tile * 32 + l31;
        const long long ns = idx64 ? (long long)src[2 * e] : (long long)src[e];
        const long long nd = idx64 ? (long long)dst[2 * e] : (long long)dst[e];
        const float* hs = h + ns * HID + l5 * 8;
        const float* hd = h + nd * HID + l5 * 8;
        f32x16 acc[4];
#pragma unroll
        for (int ct = 0; ct < 4; ++ct)
#pragma unroll
            for (int r = 0; r < 16; ++r) acc[ct][r] = 0.0f;
#pragma unroll
        for (int ks = 0; ks < 16; ++ks) {
            const float* p = (ks < 8) ? (hs + ks * 16) : (hd + (ks - 8) * 16);
            float4 f0 = *(const float4*)p;
            float4 f1 = *(const float4*)(p + 4);
            bf16x8 af;
            af[0] = (__bf16)f0.x; af[1] = (__bf16)f0.y;
            af[2] = (__bf16)f0.z; af[3] = (__bf16)f0.w;
            af[4] = (__bf16)f1.x; af[5] = (__bf16)f1.y;
            af[6] = (__bf16)f1.z; af[7] = (__bf16)f1.w;
            const int coff = ks * 32 + l5 * 16;
#pragma unroll
            for (int ct = 0; ct < 4; ++ct) {
                const int n = ct * 32 + l31;
                bf16x8 bfg = *(const bf16x8*)(smem + n * 512 + (coff ^ swz));
                acc[ct] = __builtin_amdgcn_mfma_f32_32x32x16_bf16(af, bfg,
                                                                  acc[ct], 0, 0, 0);
            }
        }
        float p[16];
#pragma unroll
        for (int r = 0; r < 16; ++r) p[r] = 0.0f;
#pragma unroll
        for (int ct = 0; ct < 4; ++ct)
#pragma unroll
            for (int r = 0; r < 16; ++r) {
                float v = acc[ct][r] + b1v[ct];
                v = v > 0.0f ? v : 0.0f;
                p[r] += v * w2v[ct];
            }
#pragma unroll
        for (int r = 0; r < 16; ++r) {
            p[r] += __shfl_xor(p[r], 1);  p[r] += __shfl_xor(p[r], 2);
            p[r] += __shfl_xor(p[r], 4);  p[r] += __shfl_xor(p[r], 8);
            p[r] += __shfl_xor(p[r], 16);
        }
        if (l31 == 0) {
#pragma unroll
            for (int g = 0; g < 4; ++g) {
                const int e0 = tile * 32 + g * 8 + l5 * 4;
                float4 o4;
                o4.x = 1.0f / (1.0f + __expf(-(p[4 * g + 0] + b2s)));
                o4.y = 1.0f / (1.0f + __expf(-(p[4 * g + 1] + b2s)));
                o4.z = 1.0f / (1.0f + __expf(-(p[4 * g + 2] + b2s)));
                o4.w = 1.0f / (1.0f + __expf(-(p[4 * g + 3] + b2s)));
                *(float4*)(out + e0) = o4;
            }
        }
    }
}

extern "C" void kernel_launch(void* const* d_in, const int* in_sizes, int n_in,
                              void* d_out, int out_size, void* d_ws, size_t ws_size,
                              hipStream_t stream) {
    const float* h  = (const float*)d_in[0];
    const float* W1 = (const float*)d_in[1];
    const float* b1 = (const float*)d_in[2];
    const float* W2 = (const float*)d_in[3];
    const float* b2 = (const float*)d_in[4];
    const int* src  = (const int*)d_in[5];
    const int* dst  = (const int*)d_in[6];
    (void)in_sizes; (void)n_in; (void)out_size;

    const size_t need = WTFRAG_OFF + 65536;
    if (ws_size >= need) {
        unsigned short* uvs  = (unsigned short*)d_ws;
        unsigned short* w1tf = (unsigned short*)((char*)d_ws + WTFRAG_OFF);
        w1_frag_kernel<<<16, 256, 0, stream>>>(W1, w1tf);
        node_gemm_kernel<<<K1BLK, 256, 0, stream>>>(h, w1tf, b1, uvs);
        edge_score_kernel<<<K2BLK, 256, 0, stream>>>(uvs, W2, b2, src, dst,
                                                     (float*)d_out);
    } else {
        edge_mlp_fallback<<<512, 256, 0, stream>>>(h, W1, b1, W2, b2, src, dst,
                                                   (float*)d_out);
    }
}